// Round 1
// 124.766 us; speedup vs baseline: 1.0213x; 1.0213x over previous
//
#include <hip/hip_runtime.h>
#include <hip/hip_bf16.h>

#define NS_TOT 2000
#define NA 1000
#define NI 5
#define NH 32
#define SHALF 1000                 // structs per block (two blocks per atom)

typedef __attribute__((ext_vector_type(2)))  float f32x2;
typedef __attribute__((ext_vector_type(8)))  short short8;   // 8 bf16 = 4 VGPR
typedef __attribute__((ext_vector_type(16))) float f32x16;   // MFMA 32x32 acc

struct f4pair  { f32x2 a, b; };
struct accpair { f32x2 p[8]; };

// Scalar Pade[5/4] tanh (same polynomial as passing R9): ~1e-3 max err.
__device__ __forceinline__ float fast_tanh(float x) {
    float z = x * x;
    float n = fmaf(z + 105.0f, z, 945.0f);
    float d = fmaf(fmaf(z, 15.0f, 420.0f), z, 945.0f);
    float r = __builtin_amdgcn_rcpf(d);
    float tv = x * n * r;
    return __builtin_amdgcn_fmed3f(tv, -1.0f, 1.0f);
}
// R9's packed form for the epilogue.
__device__ __forceinline__ f32x2 tanh_pk(f32x2 X) {
    f32x2 z = X * X;
    f32x2 n = (z + 105.0f) * z + 945.0f;
    f32x2 d = (z * 15.0f + 420.0f) * z + 945.0f;
    f32x2 r;
    r.x = __builtin_amdgcn_rcpf(d.x);
    r.y = __builtin_amdgcn_rcpf(d.y);
    f32x2 t = X * n * r;
    t.x = __builtin_amdgcn_fmed3f(t.x, -1.0f, 1.0f);
    t.y = __builtin_amdgcn_fmed3f(t.y, -1.0f, 1.0f);
    return t;
}

__device__ __forceinline__ unsigned short f2bf_rne(float x) {
    unsigned u = __float_as_uint(x);
    unsigned r = u + 0x7FFFu + ((u >> 16) & 1u);
    return (unsigned short)(r >> 16);
}
__device__ __forceinline__ unsigned pack2(float a, float b) {
    __hip_bfloat162 p = __float22bfloat162_rn(make_float2(a, b));
    unsigned u; __builtin_memcpy(&u, &p, 4); return u;
}

// R12: same MFMA structure as R11 (layout PROVEN by unchanged absmax), VALU
// diet + latency attack:
//  - b2 accumulator init hoisted out of the loop (persistent f32x16; MFMA
//    reads C non-destructively) -- kills ~32 v_mov/iter.
//  - C->B permute via v_permlane32_swap on PACKED bf16 words: one swap
//    yields {a_lo,b_lo} and {a_hi,b_hi} = two B-frag words. 12 VALU ops/tile
//    replace 8 ds_bpermute + 24 cndmask + 8 pack.
//  - g B-fragment half-zeroing dropped: afl1 is zero8 on half-1 lanes, so
//    B's k=8..15 garbage is multiplied by 0.0 (finite x 0 = 0).
//  - epilogue cross-half reduce + store fused with one permlane32_swap:
//    all 64 lanes store struct base+lane.
//  - g loads for it+1 issued before compute of it (strided 20KB gather
//    latency hidden under ~1500 cyc of tanh work).
__global__ __attribute__((amdgpu_flat_work_group_size(256, 256),
                          amdgpu_waves_per_eu(4, 4)))
void mlp_mfma(
    const float* __restrict__ g,
    const float* __restrict__ W1, const float* __restrict__ b1,
    const float* __restrict__ W2, const float* __restrict__ b2,
    const float* __restrict__ W3, const float* __restrict__ b3,
    float* __restrict__ out)
{
    const int bid   = blockIdx.x;
    const int araw  = bid % NA;
    const int chunk = bid / NA;
    const int a = (araw >> 3) + 125 * (araw & 7);   // same-XCD atom swizzle
    const int t = threadIdx.x;
    const int lane = t & 63, wid = t >> 6;
    const int l31 = lane & 31, half = lane >> 5;

    const int sbase_blk = chunk * SHALF;
    const int send      = sbase_blk + SHALF;

    __shared__ __align__(16) unsigned short sW2T[NH * NH];  // W2^T bf16 [m][k]
    __shared__ __align__(16) unsigned short sW1T[NH * 8];   // [m]{W1[0..4][m],b1[m],0,0}
    __shared__ __align__(16) float sB2[NH];
    __shared__ __align__(16) float sW3[NH];

    for (int idx = t; idx < NH * NH; idx += 256) {
        const int i = idx >> 5, j = idx & 31;
        sW2T[j * NH + i] = f2bf_rne(W2[(size_t)a * NH * NH + idx]);
    }
    if (t < NH) {
        sB2[t] = b2[a * NH + t];
        sW3[t] = W3[a * NH + t];
        const int m = t;
        #pragma unroll
        for (int i = 0; i < NI; ++i)
            sW1T[m * 8 + i] = f2bf_rne(W1[(size_t)a * NI * NH + i * NH + m]);
        sW1T[m * 8 + 5] = f2bf_rne(b1[a * NH + m]);
        sW1T[m * 8 + 6] = 0;
        sW1T[m * 8 + 7] = 0;
    }
    __syncthreads();

    // persistent fragments
    const short8 zero8 = {0,0,0,0,0,0,0,0};
    const short8 w1ld = __builtin_bit_cast(short8, *(const uint4*)(sW1T + l31 * 8));
    const short8 afl1 = half ? zero8 : w1ld;   // A[m][k]: half1 = K-pad zeros
    const short8 af0 = __builtin_bit_cast(short8, *(const uint4*)(sW2T + l31 * NH + half * 8));
    const short8 af1 = __builtin_bit_cast(short8, *(const uint4*)(sW2T + l31 * NH + 16 + half * 8));
    const float4 b2q0 = ((const float4*)sB2)[0 + half];
    const float4 b2q1 = ((const float4*)sB2)[2 + half];
    const float4 b2q2 = ((const float4*)sB2)[4 + half];
    const float4 b2q3 = ((const float4*)sB2)[6 + half];
    const float4 w3q0 = ((const float4*)sW3)[0 + half];
    const float4 w3q1 = ((const float4*)sW3)[2 + half];
    const float4 w3q2 = ((const float4*)sW3)[4 + half];
    const float4 w3q3 = ((const float4*)sW3)[6 + half];
    const float bias3 = b3[a];
    const f4pair w3p0 = __builtin_bit_cast(f4pair, w3q0);
    const f4pair w3p1 = __builtin_bit_cast(f4pair, w3q1);
    const f4pair w3p2 = __builtin_bit_cast(f4pair, w3q2);
    const f4pair w3p3 = __builtin_bit_cast(f4pair, w3q3);
    const f32x16 zacc = {0,0,0,0,0,0,0,0,0,0,0,0,0,0,0,0};
    // layer-2 bias accumulator: persistent, MFMA reads it non-destructively.
    // Same 16 regs the four b2q float4s occupied -> net-zero VGPR.
    const f32x16 b2acc = {b2q0.x, b2q0.y, b2q0.z, b2q0.w,
                          b2q1.x, b2q1.y, b2q1.z, b2q1.w,
                          b2q2.x, b2q2.y, b2q2.z, b2q2.w,
                          b2q3.x, b2q3.y, b2q3.z, b2q3.w};

    // prologue: g loads for it = 0
    float x0g, x1g, x2g, x3g, x4g;
    {
        const int s0 = sbase_blk + wid * 64 + lane;
        const int sl = (s0 < send) ? s0 : (send - 1);
        const float* gp = g + ((size_t)sl * NA + a) * NI;
        x0g = gp[0]; x1g = gp[1]; x2g = gp[2]; x3g = gp[3]; x4g = gp[4];
    }

    #pragma unroll
    for (int it = 0; it < 4; ++it) {
        const int base = sbase_blk + it * 256 + wid * 64;
        const int s = base + lane;

        // ---- prefetch next iteration's g (hide the 64-line gather) ----
        float nx0, nx1, nx2, nx3, nx4;
        if (it < 3) {
            const int sn = s + 256;
            const int sln = (sn < send) ? sn : (send - 1);
            const float* gq = g + ((size_t)sln * NA + a) * NI;
            nx0 = gq[0]; nx1 = gq[1]; nx2 = gq[2]; nx3 = gq[3]; nx4 = gq[4];
        }

        // ---- build g B-fragments (K=16, slots: g0..g4, 1.0(bias), X, X) ----
        // Half-1 words feed A's zeroed k=8..15 -> garbage * 0.0 = 0, no masking.
        const unsigned gp01 = pack2(x0g, x1g);
        const unsigned gp23 = pack2(x2g, x3g);
        const unsigned gp45 = pack2(x4g, 1.0f);
        auto gs01 = __builtin_amdgcn_permlane32_swap(gp01, gp01, false, false);
        auto gs23 = __builtin_amdgcn_permlane32_swap(gp23, gp23, false, false);
        auto gs45 = __builtin_amdgcn_permlane32_swap(gp45, gp45, false, false);
        const uint4 bu0 = make_uint4(gp01,    gp23,    gp45,    0u);
        const uint4 bu1 = make_uint4(gs01[1], gs23[1], gs45[1], 0u);  // cross-half fetch
        const short8 gb0 = __builtin_bit_cast(short8, bu0);
        const short8 gb1 = __builtin_bit_cast(short8, bu1);

        // ---- layer 1 via MFMA (bias folded in) ----
        f32x16 d0 = __builtin_amdgcn_mfma_f32_32x32x16_bf16(afl1, gb0, zacc, 0, 0, 0);
        f32x16 d1 = __builtin_amdgcn_mfma_f32_32x32x16_bf16(afl1, gb1, zacc, 0, 0, 0);

        // ---- tanh, pack to bf16, then permlane32_swap C->B permute ----
        // C row of reg r = (r&3) + 8*(r>>2) + 4*half. Packed word p[j] holds
        // rows {2j,2j+1} within this lane's row set. swap(a,b).x = {a_lo,b_lo},
        // .y = {a_hi,b_hi}: exactly B-frag words (k = half*8 + 2w, 2w+1).
        short8 bk0_0, bk1_0, bk0_1, bk1_1;
        #define TILE_CONV(DD, BK0, BK1) { \
            const unsigned p0 = pack2(fast_tanh(DD[0]),  fast_tanh(DD[1])); \
            const unsigned p1 = pack2(fast_tanh(DD[2]),  fast_tanh(DD[3])); \
            const unsigned p2 = pack2(fast_tanh(DD[4]),  fast_tanh(DD[5])); \
            const unsigned p3 = pack2(fast_tanh(DD[6]),  fast_tanh(DD[7])); \
            const unsigned p4 = pack2(fast_tanh(DD[8]),  fast_tanh(DD[9])); \
            const unsigned p5 = pack2(fast_tanh(DD[10]), fast_tanh(DD[11])); \
            const unsigned p6 = pack2(fast_tanh(DD[12]), fast_tanh(DD[13])); \
            const unsigned p7 = pack2(fast_tanh(DD[14]), fast_tanh(DD[15])); \
            auto s02 = __builtin_amdgcn_permlane32_swap(p0, p2, false, false); \
            auto s13 = __builtin_amdgcn_permlane32_swap(p1, p3, false, false); \
            auto s46 = __builtin_amdgcn_permlane32_swap(p4, p6, false, false); \
            auto s57 = __builtin_amdgcn_permlane32_swap(p5, p7, false, false); \
            const uint4 u0 = make_uint4(s02[0], s13[0], s02[1], s13[1]); \
            const uint4 u1 = make_uint4(s46[0], s57[0], s46[1], s57[1]); \
            BK0 = __builtin_bit_cast(short8, u0); \
            BK1 = __builtin_bit_cast(short8, u1); }
        TILE_CONV(d0, bk0_0, bk1_0)
        TILE_CONV(d1, bk0_1, bk1_1)
        #undef TILE_CONV

        // ---- layer 2 MFMA (bias via persistent b2acc, no per-iter init) ----
        f32x16 acc0 = __builtin_amdgcn_mfma_f32_32x32x16_bf16(af0, bk0_0, b2acc, 0, 0, 0);
        acc0 = __builtin_amdgcn_mfma_f32_32x32x16_bf16(af1, bk1_0, acc0, 0, 0, 0);
        f32x16 acc1 = __builtin_amdgcn_mfma_f32_32x32x16_bf16(af0, bk0_1, b2acc, 0, 0, 0);
        acc1 = __builtin_amdgcn_mfma_f32_32x32x16_bf16(af1, bk1_1, acc1, 0, 0, 0);

        // ---- epilogue: packed tanh + packed layer-3 dot (identical math) ----
        const accpair ap0 = __builtin_bit_cast(accpair, acc0);
        const accpair ap1 = __builtin_bit_cast(accpair, acc1);
        f32x2 p0 = {0.f, 0.f}, p1 = {0.f, 0.f};
        #define EPP(r, wpair) { \
            p0 += tanh_pk(ap0.p[r]) * (wpair); \
            p1 += tanh_pk(ap1.p[r]) * (wpair); }
        EPP(0, w3p0.a) EPP(1, w3p0.b)
        EPP(2, w3p1.a) EPP(3, w3p1.b)
        EPP(4, w3p2.a) EPP(5, w3p2.b)
        EPP(6, w3p3.a) EPP(7, w3p3.b)
        #undef EPP
        const float e0 = p0.x + p0.y;
        const float e1 = p1.x + p1.y;
        // One swap fuses both cross-half reductions; every lane stores its
        // own struct: half0 lane l -> e0 sum (struct base+l), half1 -> e1.
        auto es = __builtin_amdgcn_permlane32_swap(__float_as_uint(e0),
                                                   __float_as_uint(e1),
                                                   false, false);
        const float etot = __uint_as_float(es[0]) + __uint_as_float(es[1]);
        if (s < send) out[(size_t)s * NA + a] = etot + bias3;

        if (it < 3) { x0g = nx0; x1g = nx1; x2g = nx2; x3g = nx3; x4g = nx4; }
    }
}

extern "C" void kernel_launch(void* const* d_in, const int* in_sizes, int n_in,
                              void* d_out, int out_size, void* d_ws, size_t ws_size,
                              hipStream_t stream) {
    const float* g  = (const float*)d_in[0];
    const float* W1 = (const float*)d_in[1];
    const float* b1 = (const float*)d_in[2];
    const float* W2 = (const float*)d_in[3];
    const float* b2 = (const float*)d_in[4];
    const float* W3 = (const float*)d_in[5];
    const float* b3 = (const float*)d_in[6];
    float* out = (float*)d_out;
    mlp_mfma<<<dim3(NA * 2), dim3(256), 0, stream>>>(g, W1, b1, W2, b2, W3, b3, out);
}

// Round 2
// 120.882 us; speedup vs baseline: 1.0542x; 1.0321x over previous
//
#include <hip/hip_runtime.h>
#include <hip/hip_bf16.h>

#define NS_TOT 2000
#define NA 1000
#define NI 5
#define NH 32
#define SHALF 1000                 // structs per block (two blocks per atom)

typedef __attribute__((ext_vector_type(2)))  float f32x2;
typedef __attribute__((ext_vector_type(8)))  short short8;   // 8 bf16 = 4 VGPR
typedef __attribute__((ext_vector_type(16))) float f32x16;   // MFMA 32x32 acc

struct f4pair  { f32x2 a, b; };
struct accpair { f32x2 p[8]; };

// Packed Pade[5/4] tanh (same polynomial/op-order as scalar fast_tanh under
// -ffp-contract: bit-identical). f32x2 ops lower to v_pk_*_f32 on gfx950,
// halving issue slots for everything except rcp/fmed3.
__device__ __forceinline__ f32x2 tanh_pk(f32x2 X) {
    f32x2 z = X * X;
    f32x2 n = (z + 105.0f) * z + 945.0f;
    f32x2 d = (z * 15.0f + 420.0f) * z + 945.0f;
    f32x2 r;
    r.x = __builtin_amdgcn_rcpf(d.x);
    r.y = __builtin_amdgcn_rcpf(d.y);
    f32x2 t = X * n * r;
    t.x = __builtin_amdgcn_fmed3f(t.x, -1.0f, 1.0f);
    t.y = __builtin_amdgcn_fmed3f(t.y, -1.0f, 1.0f);
    return t;
}

__device__ __forceinline__ unsigned short f2bf_rne(float x) {
    unsigned u = __float_as_uint(x);
    unsigned r = u + 0x7FFFu + ((u >> 16) & 1u);
    return (unsigned short)(r >> 16);
}
__device__ __forceinline__ unsigned pack2(float a, float b) {
    __hip_bfloat162 p = __float22bfloat162_rn(make_float2(a, b));
    unsigned u; __builtin_memcpy(&u, &p, 4); return u;
}
// tanh two C-values and pack to one bf16x2 word (mid-layer path).
__device__ __forceinline__ unsigned tanh2_pack(float a, float b) {
    f32x2 X = {a, b};
    f32x2 t = tanh_pk(X);
    return pack2(t.x, t.y);
}

// R13: R12 structure (permlane C->B permute, persistent b2acc, prefetch)
// + two changes:
//  - mid-layer tanh evaluated in f32x2 packed form (tanh2_pack): the 16
//    C-pairs per tile were tanh'd scalar then packed anyway; packed form
//    cuts ~112 issue slots/wave-iter with bit-identical math.
//  - amdgpu_waves_per_eu(4,8): R12 measured VGPR_Count=64 == the 8-waves/EU
//    boundary, while (4,4) capped occupancy at 4 waves/EU. Live set is
//    PROVEN 64 (unlike R11's ~100), so the allocator's 64-VGPR target is
//    already met -> 8 WG/CU resident, whole 2000-WG grid ~co-resident.
__global__ __attribute__((amdgpu_flat_work_group_size(256, 256),
                          amdgpu_waves_per_eu(4, 8)))
void mlp_mfma(
    const float* __restrict__ g,
    const float* __restrict__ W1, const float* __restrict__ b1,
    const float* __restrict__ W2, const float* __restrict__ b2,
    const float* __restrict__ W3, const float* __restrict__ b3,
    float* __restrict__ out)
{
    const int bid   = blockIdx.x;
    const int araw  = bid % NA;
    const int chunk = bid / NA;
    const int a = (araw >> 3) + 125 * (araw & 7);   // same-XCD atom swizzle
    const int t = threadIdx.x;
    const int lane = t & 63, wid = t >> 6;
    const int l31 = lane & 31, half = lane >> 5;

    const int sbase_blk = chunk * SHALF;
    const int send      = sbase_blk + SHALF;

    __shared__ __align__(16) unsigned short sW2T[NH * NH];  // W2^T bf16 [m][k]
    __shared__ __align__(16) unsigned short sW1T[NH * 8];   // [m]{W1[0..4][m],b1[m],0,0}
    __shared__ __align__(16) float sB2[NH];
    __shared__ __align__(16) float sW3[NH];

    for (int idx = t; idx < NH * NH; idx += 256) {
        const int i = idx >> 5, j = idx & 31;
        sW2T[j * NH + i] = f2bf_rne(W2[(size_t)a * NH * NH + idx]);
    }
    if (t < NH) {
        sB2[t] = b2[a * NH + t];
        sW3[t] = W3[a * NH + t];
        const int m = t;
        #pragma unroll
        for (int i = 0; i < NI; ++i)
            sW1T[m * 8 + i] = f2bf_rne(W1[(size_t)a * NI * NH + i * NH + m]);
        sW1T[m * 8 + 5] = f2bf_rne(b1[a * NH + m]);
        sW1T[m * 8 + 6] = 0;
        sW1T[m * 8 + 7] = 0;
    }
    __syncthreads();

    // persistent fragments
    const short8 zero8 = {0,0,0,0,0,0,0,0};
    const short8 w1ld = __builtin_bit_cast(short8, *(const uint4*)(sW1T + l31 * 8));
    const short8 afl1 = half ? zero8 : w1ld;   // A[m][k]: half1 = K-pad zeros
    const short8 af0 = __builtin_bit_cast(short8, *(const uint4*)(sW2T + l31 * NH + half * 8));
    const short8 af1 = __builtin_bit_cast(short8, *(const uint4*)(sW2T + l31 * NH + 16 + half * 8));
    const float4 b2q0 = ((const float4*)sB2)[0 + half];
    const float4 b2q1 = ((const float4*)sB2)[2 + half];
    const float4 b2q2 = ((const float4*)sB2)[4 + half];
    const float4 b2q3 = ((const float4*)sB2)[6 + half];
    const float4 w3q0 = ((const float4*)sW3)[0 + half];
    const float4 w3q1 = ((const float4*)sW3)[2 + half];
    const float4 w3q2 = ((const float4*)sW3)[4 + half];
    const float4 w3q3 = ((const float4*)sW3)[6 + half];
    const float bias3 = b3[a];
    const f4pair w3p0 = __builtin_bit_cast(f4pair, w3q0);
    const f4pair w3p1 = __builtin_bit_cast(f4pair, w3q1);
    const f4pair w3p2 = __builtin_bit_cast(f4pair, w3q2);
    const f4pair w3p3 = __builtin_bit_cast(f4pair, w3q3);
    const f32x16 zacc = {0,0,0,0,0,0,0,0,0,0,0,0,0,0,0,0};
    // layer-2 bias accumulator: persistent, MFMA reads it non-destructively.
    const f32x16 b2acc = {b2q0.x, b2q0.y, b2q0.z, b2q0.w,
                          b2q1.x, b2q1.y, b2q1.z, b2q1.w,
                          b2q2.x, b2q2.y, b2q2.z, b2q2.w,
                          b2q3.x, b2q3.y, b2q3.z, b2q3.w};

    // prologue: g loads for it = 0
    float x0g, x1g, x2g, x3g, x4g;
    {
        const int s0 = sbase_blk + wid * 64 + lane;
        const int sl = (s0 < send) ? s0 : (send - 1);
        const float* gp = g + ((size_t)sl * NA + a) * NI;
        x0g = gp[0]; x1g = gp[1]; x2g = gp[2]; x3g = gp[3]; x4g = gp[4];
    }

    #pragma unroll
    for (int it = 0; it < 4; ++it) {
        const int base = sbase_blk + it * 256 + wid * 64;
        const int s = base + lane;

        // ---- prefetch next iteration's g (hide the 64-line gather) ----
        float nx0, nx1, nx2, nx3, nx4;
        if (it < 3) {
            const int sn = s + 256;
            const int sln = (sn < send) ? sn : (send - 1);
            const float* gq = g + ((size_t)sln * NA + a) * NI;
            nx0 = gq[0]; nx1 = gq[1]; nx2 = gq[2]; nx3 = gq[3]; nx4 = gq[4];
        }

        // ---- build g B-fragments (K=16, slots: g0..g4, 1.0(bias), X, X) ----
        // Half-1 words feed A's zeroed k=8..15 -> garbage * 0.0 = 0, no masking.
        const unsigned gp01 = pack2(x0g, x1g);
        const unsigned gp23 = pack2(x2g, x3g);
        const unsigned gp45 = pack2(x4g, 1.0f);
        auto gs01 = __builtin_amdgcn_permlane32_swap(gp01, gp01, false, false);
        auto gs23 = __builtin_amdgcn_permlane32_swap(gp23, gp23, false, false);
        auto gs45 = __builtin_amdgcn_permlane32_swap(gp45, gp45, false, false);
        const uint4 bu0 = make_uint4(gp01,    gp23,    gp45,    0u);
        const uint4 bu1 = make_uint4(gs01[1], gs23[1], gs45[1], 0u);  // cross-half fetch
        const short8 gb0 = __builtin_bit_cast(short8, bu0);
        const short8 gb1 = __builtin_bit_cast(short8, bu1);

        // ---- layer 1 via MFMA (bias folded in) ----
        f32x16 d0 = __builtin_amdgcn_mfma_f32_32x32x16_bf16(afl1, gb0, zacc, 0, 0, 0);
        f32x16 d1 = __builtin_amdgcn_mfma_f32_32x32x16_bf16(afl1, gb1, zacc, 0, 0, 0);

        // ---- packed tanh + cvt_pk, then permlane32_swap C->B permute ----
        // C row of reg r = (r&3) + 8*(r>>2) + 4*half. Packed word p[j] holds
        // rows {2j,2j+1} within this lane's row set. swap(a,b).x = {a_lo,b_lo},
        // .y = {a_hi,b_hi}: exactly B-frag words (k = half*8 + 2w, 2w+1).
        short8 bk0_0, bk1_0, bk0_1, bk1_1;
        #define TILE_CONV(DD, BK0, BK1) { \
            const unsigned p0 = tanh2_pack(DD[0],  DD[1]); \
            const unsigned p1 = tanh2_pack(DD[2],  DD[3]); \
            const unsigned p2 = tanh2_pack(DD[4],  DD[5]); \
            const unsigned p3 = tanh2_pack(DD[6],  DD[7]); \
            const unsigned p4 = tanh2_pack(DD[8],  DD[9]); \
            const unsigned p5 = tanh2_pack(DD[10], DD[11]); \
            const unsigned p6 = tanh2_pack(DD[12], DD[13]); \
            const unsigned p7 = tanh2_pack(DD[14], DD[15]); \
            auto s02 = __builtin_amdgcn_permlane32_swap(p0, p2, false, false); \
            auto s13 = __builtin_amdgcn_permlane32_swap(p1, p3, false, false); \
            auto s46 = __builtin_amdgcn_permlane32_swap(p4, p6, false, false); \
            auto s57 = __builtin_amdgcn_permlane32_swap(p5, p7, false, false); \
            const uint4 u0 = make_uint4(s02[0], s13[0], s02[1], s13[1]); \
            const uint4 u1 = make_uint4(s46[0], s57[0], s46[1], s57[1]); \
            BK0 = __builtin_bit_cast(short8, u0); \
            BK1 = __builtin_bit_cast(short8, u1); }
        TILE_CONV(d0, bk0_0, bk1_0)
        TILE_CONV(d1, bk0_1, bk1_1)
        #undef TILE_CONV

        // ---- layer 2 MFMA (bias via persistent b2acc, no per-iter init) ----
        f32x16 acc0 = __builtin_amdgcn_mfma_f32_32x32x16_bf16(af0, bk0_0, b2acc, 0, 0, 0);
        acc0 = __builtin_amdgcn_mfma_f32_32x32x16_bf16(af1, bk1_0, acc0, 0, 0, 0);
        f32x16 acc1 = __builtin_amdgcn_mfma_f32_32x32x16_bf16(af0, bk0_1, b2acc, 0, 0, 0);
        acc1 = __builtin_amdgcn_mfma_f32_32x32x16_bf16(af1, bk1_1, acc1, 0, 0, 0);

        // ---- epilogue: packed tanh + packed layer-3 dot (identical math) ----
        const accpair ap0 = __builtin_bit_cast(accpair, acc0);
        const accpair ap1 = __builtin_bit_cast(accpair, acc1);
        f32x2 p0 = {0.f, 0.f}, p1 = {0.f, 0.f};
        #define EPP(r, wpair) { \
            p0 += tanh_pk(ap0.p[r]) * (wpair); \
            p1 += tanh_pk(ap1.p[r]) * (wpair); }
        EPP(0, w3p0.a) EPP(1, w3p0.b)
        EPP(2, w3p1.a) EPP(3, w3p1.b)
        EPP(4, w3p2.a) EPP(5, w3p2.b)
        EPP(6, w3p3.a) EPP(7, w3p3.b)
        #undef EPP
        const float e0 = p0.x + p0.y;
        const float e1 = p1.x + p1.y;
        // One swap fuses both cross-half reductions; every lane stores its
        // own struct: half0 lane l -> e0 sum (struct base+l), half1 -> e1.
        auto es = __builtin_amdgcn_permlane32_swap(__float_as_uint(e0),
                                                   __float_as_uint(e1),
                                                   false, false);
        const float etot = __uint_as_float(es[0]) + __uint_as_float(es[1]);
        if (s < send) out[(size_t)s * NA + a] = etot + bias3;

        if (it < 3) { x0g = nx0; x1g = nx1; x2g = nx2; x3g = nx3; x4g = nx4; }
    }
}

extern "C" void kernel_launch(void* const* d_in, const int* in_sizes, int n_in,
                              void* d_out, int out_size, void* d_ws, size_t ws_size,
                              hipStream_t stream) {
    const float* g  = (const float*)d_in[0];
    const float* W1 = (const float*)d_in[1];
    const float* b1 = (const float*)d_in[2];
    const float* W2 = (const float*)d_in[3];
    const float* b2 = (const float*)d_in[4];
    const float* W3 = (const float*)d_in[5];
    const float* b3 = (const float*)d_in[6];
    float* out = (float*)d_out;
    mlp_mfma<<<dim3(NA * 2), dim3(256), 0, stream>>>(g, W1, b1, W2, b2, W3, b3, out);
}

// Round 3
// 120.498 us; speedup vs baseline: 1.0575x; 1.0032x over previous
//
#include <hip/hip_runtime.h>
#include <hip/hip_bf16.h>

#define NS_TOT 2000
#define NA 1000
#define NI 5
#define NH 32
#define SHALF 1000                 // structs per block (two blocks per atom)
#define W2LD 40                    // sW2T leading dim: 80B rows = 16B-aligned,
                                   // bank-spread staging writes (was 16-way)

typedef __attribute__((ext_vector_type(2)))  float f32x2;
typedef __attribute__((ext_vector_type(8)))  short short8;   // 8 bf16 = 4 VGPR
typedef __attribute__((ext_vector_type(16))) float f32x16;   // MFMA 32x32 acc

struct f4pair  { f32x2 a, b; };
struct accpair { f32x2 p[8]; };

// Packed Pade[5/4] tanh (bit-identical polynomial/op-order to all passing
// rounds). f32x2 ops lower to v_pk_*_f32 (verified: R13's mid-layer
// packing saved exactly the predicted slot count).
__device__ __forceinline__ f32x2 tanh_pk(f32x2 X) {
    f32x2 z = X * X;
    f32x2 n = (z + 105.0f) * z + 945.0f;
    f32x2 d = (z * 15.0f + 420.0f) * z + 945.0f;
    f32x2 r;
    r.x = __builtin_amdgcn_rcpf(d.x);
    r.y = __builtin_amdgcn_rcpf(d.y);
    f32x2 t = X * n * r;
    t.x = __builtin_amdgcn_fmed3f(t.x, -1.0f, 1.0f);
    t.y = __builtin_amdgcn_fmed3f(t.y, -1.0f, 1.0f);
    return t;
}

__device__ __forceinline__ unsigned short f2bf_rne(float x) {
    unsigned u = __float_as_uint(x);
    unsigned r = u + 0x7FFFu + ((u >> 16) & 1u);
    return (unsigned short)(r >> 16);
}
__device__ __forceinline__ unsigned pack2(float a, float b) {
    __hip_bfloat162 p = __float22bfloat162_rn(make_float2(a, b));
    unsigned u; __builtin_memcpy(&u, &p, 4); return u;
}
// tanh two C-values and pack to one bf16x2 word (mid-layer path).
__device__ __forceinline__ unsigned tanh2_pack(float a, float b) {
    f32x2 X = {a, b};
    f32x2 t = tanh_pk(X);
    return pack2(t.x, t.y);
}

// R14: R13 math (bit-identical) + cross-iteration software pipeline.
//  - it+1's front-end (g-frag build + both L1 MFMAs) issues right after
//    it's L2 MFMAs, BEFORE it's epilogue: the ~600-cyc epilogue VALU now
//    overlaps next-iter MFMA execution, and the next TILE_CONV finds d0/d1
//    already resolved (MFMA-result waits leave the critical path).
//  - g loads 2 iterations ahead (latency stays covered).
//  - epilogue drains acc0 fully then acc1 (frees 16 regs early; carried
//    d0/d1 adds 32 live regs across the epilogue).
//  - waves_per_eu(3,4): live set now >64 regs; (3,4) = 170-reg budget floor,
//    no spill (R11 lesson: never demand occupancy the live set can't fit).
//    Measured occupancy never exceeded ~31% anyway, so max=4 loses nothing.
//  - sW2T leading dim 32->40 ushorts: staging writes were the entire
//    1.152M SQ_LDS_BANK_CONFLICT (16-way on 64B strides).
__global__ __attribute__((amdgpu_flat_work_group_size(256, 256),
                          amdgpu_waves_per_eu(3, 4)))
void mlp_mfma(
    const float* __restrict__ g,
    const float* __restrict__ W1, const float* __restrict__ b1,
    const float* __restrict__ W2, const float* __restrict__ b2,
    const float* __restrict__ W3, const float* __restrict__ b3,
    float* __restrict__ out)
{
    const int bid   = blockIdx.x;
    const int araw  = bid % NA;
    const int chunk = bid / NA;
    const int a = (araw >> 3) + 125 * (araw & 7);   // same-XCD atom swizzle
    const int t = threadIdx.x;
    const int lane = t & 63, wid = t >> 6;
    const int l31 = lane & 31, half = lane >> 5;

    const int sbase_blk = chunk * SHALF;
    const int send      = sbase_blk + SHALF;

    __shared__ __align__(16) unsigned short sW2T[NH * W2LD];  // W2^T bf16 [m][k]
    __shared__ __align__(16) unsigned short sW1T[NH * 8];     // [m]{W1[0..4][m],b1[m],0,0}
    __shared__ __align__(16) float sB2[NH];
    __shared__ __align__(16) float sW3[NH];

    for (int idx = t; idx < NH * NH; idx += 256) {
        const int i = idx >> 5, j = idx & 31;       // i = k row of W2, j = m col
        sW2T[j * W2LD + i] = f2bf_rne(W2[(size_t)a * NH * NH + idx]);
    }
    if (t < NH) {
        sB2[t] = b2[a * NH + t];
        sW3[t] = W3[a * NH + t];
        const int m = t;
        #pragma unroll
        for (int i = 0; i < NI; ++i)
            sW1T[m * 8 + i] = f2bf_rne(W1[(size_t)a * NI * NH + i * NH + m]);
        sW1T[m * 8 + 5] = f2bf_rne(b1[a * NH + m]);
        sW1T[m * 8 + 6] = 0;
        sW1T[m * 8 + 7] = 0;
    }
    __syncthreads();

    // persistent fragments
    const short8 zero8 = {0,0,0,0,0,0,0,0};
    const short8 w1ld = __builtin_bit_cast(short8, *(const uint4*)(sW1T + l31 * 8));
    const short8 afl1 = half ? zero8 : w1ld;   // A[m][k]: half1 = K-pad zeros
    const short8 af0 = __builtin_bit_cast(short8, *(const uint4*)(sW2T + l31 * W2LD + half * 8));
    const short8 af1 = __builtin_bit_cast(short8, *(const uint4*)(sW2T + l31 * W2LD + 16 + half * 8));
    const float4 b2q0 = ((const float4*)sB2)[0 + half];
    const float4 b2q1 = ((const float4*)sB2)[2 + half];
    const float4 b2q2 = ((const float4*)sB2)[4 + half];
    const float4 b2q3 = ((const float4*)sB2)[6 + half];
    const float4 w3q0 = ((const float4*)sW3)[0 + half];
    const float4 w3q1 = ((const float4*)sW3)[2 + half];
    const float4 w3q2 = ((const float4*)sW3)[4 + half];
    const float4 w3q3 = ((const float4*)sW3)[6 + half];
    const float bias3 = b3[a];
    const f4pair w3p0 = __builtin_bit_cast(f4pair, w3q0);
    const f4pair w3p1 = __builtin_bit_cast(f4pair, w3q1);
    const f4pair w3p2 = __builtin_bit_cast(f4pair, w3q2);
    const f4pair w3p3 = __builtin_bit_cast(f4pair, w3q3);
    const f32x16 zacc = {0,0,0,0,0,0,0,0,0,0,0,0,0,0,0,0};
    // layer-2 bias accumulator: persistent, MFMA reads it non-destructively.
    const f32x16 b2acc = {b2q0.x, b2q0.y, b2q0.z, b2q0.w,
                          b2q1.x, b2q1.y, b2q1.z, b2q1.w,
                          b2q2.x, b2q2.y, b2q2.z, b2q2.w,
                          b2q3.x, b2q3.y, b2q3.z, b2q3.w};

    // g-frag build + L1 MFMAs (K slots: g0..g4, 1.0(bias), X, X; half-1
    // garbage words feed A's zeroed k=8..15 -> x*0 = 0, no masking).
    #define BUILD_L1(AX0, AX1, AX2, AX3, AX4) { \
        const unsigned gp01 = pack2(AX0, AX1); \
        const unsigned gp23 = pack2(AX2, AX3); \
        const unsigned gp45 = pack2(AX4, 1.0f); \
        auto gs01 = __builtin_amdgcn_permlane32_swap(gp01, gp01, false, false); \
        auto gs23 = __builtin_amdgcn_permlane32_swap(gp23, gp23, false, false); \
        auto gs45 = __builtin_amdgcn_permlane32_swap(gp45, gp45, false, false); \
        const uint4 bu0 = make_uint4(gp01,    gp23,    gp45,    0u); \
        const uint4 bu1 = make_uint4(gs01[1], gs23[1], gs45[1], 0u); \
        const short8 gb0 = __builtin_bit_cast(short8, bu0); \
        const short8 gb1 = __builtin_bit_cast(short8, bu1); \
        d0 = __builtin_amdgcn_mfma_f32_32x32x16_bf16(afl1, gb0, zacc, 0, 0, 0); \
        d1 = __builtin_amdgcn_mfma_f32_32x32x16_bf16(afl1, gb1, zacc, 0, 0, 0); }

    // prologue: g for it=0 (x*) and it=1 (y*); front-end of it=0.
    float x0g, x1g, x2g, x3g, x4g;
    float y0g, y1g, y2g, y3g, y4g;
    {
        const int s0 = sbase_blk + wid * 64 + lane;
        const float* gp = g + ((size_t)s0 * NA + a) * NI;
        x0g = gp[0]; x1g = gp[1]; x2g = gp[2]; x3g = gp[3]; x4g = gp[4];
        const int s1 = s0 + 256;                       // always < send for it=1
        const float* gq = g + ((size_t)s1 * NA + a) * NI;
        y0g = gq[0]; y1g = gq[1]; y2g = gq[2]; y3g = gq[3]; y4g = gq[4];
    }
    f32x16 d0, d1;
    BUILD_L1(x0g, x1g, x2g, x3g, x4g)

    #pragma unroll
    for (int it = 0; it < 4; ++it) {
        const int base = sbase_blk + it * 256 + wid * 64;
        const int s = base + lane;

        // ---- mid-layer: packed tanh + cvt_pk, permlane32_swap C->B ----
        // C row of reg r = (r&3) + 8*(r>>2) + 4*half. Packed word p[j] holds
        // rows {2j,2j+1} of this lane's row set. swap(a,b).x = {a_lo,b_lo},
        // .y = {a_hi,b_hi}: exactly B-frag words (k = half*8 + 2w, 2w+1).
        short8 bk0_0, bk1_0, bk0_1, bk1_1;
        #define TILE_CONV(DD, BK0, BK1) { \
            const unsigned p0 = tanh2_pack(DD[0],  DD[1]); \
            const unsigned p1 = tanh2_pack(DD[2],  DD[3]); \
            const unsigned p2 = tanh2_pack(DD[4],  DD[5]); \
            const unsigned p3 = tanh2_pack(DD[6],  DD[7]); \
            const unsigned p4 = tanh2_pack(DD[8],  DD[9]); \
            const unsigned p5 = tanh2_pack(DD[10], DD[11]); \
            const unsigned p6 = tanh2_pack(DD[12], DD[13]); \
            const unsigned p7 = tanh2_pack(DD[14], DD[15]); \
            auto s02 = __builtin_amdgcn_permlane32_swap(p0, p2, false, false); \
            auto s13 = __builtin_amdgcn_permlane32_swap(p1, p3, false, false); \
            auto s46 = __builtin_amdgcn_permlane32_swap(p4, p6, false, false); \
            auto s57 = __builtin_amdgcn_permlane32_swap(p5, p7, false, false); \
            const uint4 u0 = make_uint4(s02[0], s13[0], s02[1], s13[1]); \
            const uint4 u1 = make_uint4(s46[0], s57[0], s46[1], s57[1]); \
            BK0 = __builtin_bit_cast(short8, u0); \
            BK1 = __builtin_bit_cast(short8, u1); }
        TILE_CONV(d0, bk0_0, bk1_0)
        TILE_CONV(d1, bk0_1, bk1_1)
        #undef TILE_CONV

        // ---- layer 2 MFMA (bias via persistent b2acc) ----
        f32x16 acc0 = __builtin_amdgcn_mfma_f32_32x32x16_bf16(af0, bk0_0, b2acc, 0, 0, 0);
        acc0 = __builtin_amdgcn_mfma_f32_32x32x16_bf16(af1, bk1_0, acc0, 0, 0, 0);
        f32x16 acc1 = __builtin_amdgcn_mfma_f32_32x32x16_bf16(af0, bk0_1, b2acc, 0, 0, 0);
        acc1 = __builtin_amdgcn_mfma_f32_32x32x16_bf16(af1, bk1_1, acc1, 0, 0, 0);

        // ---- next-iter front-end BEFORE the epilogue: L1 MFMAs of it+1
        // execute on the (95%-idle) matrix pipe under the epilogue VALU. ----
        if (it < 3) {
            BUILD_L1(y0g, y1g, y2g, y3g, y4g)
        }
        // refill y* for it+2 (2-ahead distance keeps latency covered; y*
        // was consumed by BUILD_L1 above).
        if (it < 2) {
            const int sn = s + 512;
            const int sln = (sn < send) ? sn : (send - 1);
            const float* gq = g + ((size_t)sln * NA + a) * NI;
            y0g = gq[0]; y1g = gq[1]; y2g = gq[2]; y3g = gq[3]; y4g = gq[4];
        }

        // ---- epilogue: acc0 fully, then acc1 (early reg release) ----
        const accpair ap0 = __builtin_bit_cast(accpair, acc0);
        f32x2 p0 = {0.f, 0.f};
        p0 += tanh_pk(ap0.p[0]) * w3p0.a;  p0 += tanh_pk(ap0.p[1]) * w3p0.b;
        p0 += tanh_pk(ap0.p[2]) * w3p1.a;  p0 += tanh_pk(ap0.p[3]) * w3p1.b;
        p0 += tanh_pk(ap0.p[4]) * w3p2.a;  p0 += tanh_pk(ap0.p[5]) * w3p2.b;
        p0 += tanh_pk(ap0.p[6]) * w3p3.a;  p0 += tanh_pk(ap0.p[7]) * w3p3.b;
        const float e0 = p0.x + p0.y;
        const accpair ap1 = __builtin_bit_cast(accpair, acc1);
        f32x2 p1 = {0.f, 0.f};
        p1 += tanh_pk(ap1.p[0]) * w3p0.a;  p1 += tanh_pk(ap1.p[1]) * w3p0.b;
        p1 += tanh_pk(ap1.p[2]) * w3p1.a;  p1 += tanh_pk(ap1.p[3]) * w3p1.b;
        p1 += tanh_pk(ap1.p[4]) * w3p2.a;  p1 += tanh_pk(ap1.p[5]) * w3p2.b;
        p1 += tanh_pk(ap1.p[6]) * w3p3.a;  p1 += tanh_pk(ap1.p[7]) * w3p3.b;
        const float e1 = p1.x + p1.y;
        // One swap fuses both cross-half reductions; every lane stores its
        // own struct: half0 lane l -> e0 sum (struct base+l), half1 -> e1.
        auto es = __builtin_amdgcn_permlane32_swap(__float_as_uint(e0),
                                                   __float_as_uint(e1),
                                                   false, false);
        const float etot = __uint_as_float(es[0]) + __uint_as_float(es[1]);
        if (s < send) out[(size_t)s * NA + a] = etot + bias3;
    }
    #undef BUILD_L1
}

extern "C" void kernel_launch(void* const* d_in, const int* in_sizes, int n_in,
                              void* d_out, int out_size, void* d_ws, size_t ws_size,
                              hipStream_t stream) {
    const float* g  = (const float*)d_in[0];
    const float* W1 = (const float*)d_in[1];
    const float* b1 = (const float*)d_in[2];
    const float* W2 = (const float*)d_in[3];
    const float* b2 = (const float*)d_in[4];
    const float* W3 = (const float*)d_in[5];
    const float* b3 = (const float*)d_in[6];
    float* out = (float*)d_out;
    mlp_mfma<<<dim3(NA * 2), dim3(256), 0, stream>>>(g, W1, b1, W2, b2, W3, b3, out);
}

// Round 5
// 119.687 us; speedup vs baseline: 1.0647x; 1.0068x over previous
//
#include <hip/hip_runtime.h>
#include <hip/hip_bf16.h>

#define NS_TOT 2000
#define NA 1000
#define NI 5
#define NH 32
#define SHALF 1000                 // structs per block (two blocks per atom)
#define W2LD 40                    // sW2T leading dim: 80B rows = 16B-aligned,
                                   // bank-spread staging writes (was 16-way)

typedef __attribute__((ext_vector_type(2)))  float f32x2;
typedef __attribute__((ext_vector_type(8)))  short short8;   // 8 bf16 = 4 VGPR
typedef __attribute__((ext_vector_type(16))) float f32x16;   // MFMA 32x32 acc

struct f4pair  { f32x2 a, b; };
struct accpair { f32x2 p[8]; };

// Packed Pade[5/4] tanh. R15: ONE rcp per pair via paired reciprocal
// (r = rcp(dx*dy); 1/dx = r*dy, 1/dy = r*dx). d >= 945 > 0 always and
// dx*dy <= ~6e8 (pre-activations are O(6)), so no overflow/sign issues;
// added rel err ~3e-7 << the 1e-3 Pade error. Halves TRANS-pipe issue
// occupancy (64 -> 32 quarter-rate rcps per wave-iter).
__device__ __forceinline__ f32x2 tanh_pk(f32x2 X) {
    f32x2 z = X * X;
    f32x2 n = (z + 105.0f) * z + 945.0f;
    f32x2 d = (z * 15.0f + 420.0f) * z + 945.0f;
    const float rr = __builtin_amdgcn_rcpf(d.x * d.y);
    f32x2 r;
    r.x = rr * d.y;
    r.y = rr * d.x;
    f32x2 t = X * n * r;
    t.x = __builtin_amdgcn_fmed3f(t.x, -1.0f, 1.0f);
    t.y = __builtin_amdgcn_fmed3f(t.y, -1.0f, 1.0f);
    return t;
}

__device__ __forceinline__ unsigned short f2bf_rne(float x) {
    unsigned u = __float_as_uint(x);
    unsigned r = u + 0x7FFFu + ((u >> 16) & 1u);
    return (unsigned short)(r >> 16);
}
__device__ __forceinline__ unsigned pack2(float a, float b) {
    __hip_bfloat162 p = __float22bfloat162_rn(make_float2(a, b));
    unsigned u; __builtin_memcpy(&u, &p, 4); return u;
}
// tanh two C-values and pack to one bf16x2 word (mid-layer path).
__device__ __forceinline__ unsigned tanh2_pack(float a, float b) {
    f32x2 X = {a, b};
    f32x2 t = tanh_pk(X);
    return pack2(t.x, t.y);
}

// R15 (resubmit; R4's failure was container infra, kernel never ran):
// R14's pipeline FORCED with sched_barrier(0) fences. R14's failure
// signature was VGPR_Count staying 64: the scheduler sank BUILD_L1(it+1)
// back to its use site (no fence stopped it), undoing the pipeline. Now:
//   TILE_CONV(it) | SB | BUILD_L1(it+1) [2 L1 MFMAs issue here] | SB |
//   L2 MFMAs(it) + loads + epilogue(it)
// The epilogue (~400+ cyc VALU) overlaps L1-MFMA execution of it+1, and
// the scheduler may still interleave epilogue(it) with TILE_CONV(it+1)
// (no fence between them) for extra ILP. Carried d0/d1 + acc0/acc1 push
// the live set to ~130: waves_per_eu(3,4) = 170-reg budget, no spill,
// HW occupancy floor 3 waves/EU >= the ~2.4 we actually get.
__global__ __attribute__((amdgpu_flat_work_group_size(256, 256),
                          amdgpu_waves_per_eu(3, 4)))
void mlp_mfma(
    const float* __restrict__ g,
    const float* __restrict__ W1, const float* __restrict__ b1,
    const float* __restrict__ W2, const float* __restrict__ b2,
    const float* __restrict__ W3, const float* __restrict__ b3,
    float* __restrict__ out)
{
    const int bid   = blockIdx.x;
    const int araw  = bid % NA;
    const int chunk = bid / NA;
    const int a = (araw >> 3) + 125 * (araw & 7);   // same-XCD atom swizzle
    const int t = threadIdx.x;
    const int lane = t & 63, wid = t >> 6;
    const int l31 = lane & 31, half = lane >> 5;

    const int sbase_blk = chunk * SHALF;
    const int send      = sbase_blk + SHALF;

    __shared__ __align__(16) unsigned short sW2T[NH * W2LD];  // W2^T bf16 [m][k]
    __shared__ __align__(16) unsigned short sW1T[NH * 8];     // [m]{W1[0..4][m],b1[m],0,0}
    __shared__ __align__(16) float sB2[NH];
    __shared__ __align__(16) float sW3[NH];

    for (int idx = t; idx < NH * NH; idx += 256) {
        const int i = idx >> 5, j = idx & 31;       // i = k row of W2, j = m col
        sW2T[j * W2LD + i] = f2bf_rne(W2[(size_t)a * NH * NH + idx]);
    }
    if (t < NH) {
        sB2[t] = b2[a * NH + t];
        sW3[t] = W3[a * NH + t];
        const int m = t;
        #pragma unroll
        for (int i = 0; i < NI; ++i)
            sW1T[m * 8 + i] = f2bf_rne(W1[(size_t)a * NI * NH + i * NH + m]);
        sW1T[m * 8 + 5] = f2bf_rne(b1[a * NH + m]);
        sW1T[m * 8 + 6] = 0;
        sW1T[m * 8 + 7] = 0;
    }
    __syncthreads();

    // persistent fragments
    const short8 zero8 = {0,0,0,0,0,0,0,0};
    const short8 w1ld = __builtin_bit_cast(short8, *(const uint4*)(sW1T + l31 * 8));
    const short8 afl1 = half ? zero8 : w1ld;   // A[m][k]: half1 = K-pad zeros
    const short8 af0 = __builtin_bit_cast(short8, *(const uint4*)(sW2T + l31 * W2LD + half * 8));
    const short8 af1 = __builtin_bit_cast(short8, *(const uint4*)(sW2T + l31 * W2LD + 16 + half * 8));
    const float4 b2q0 = ((const float4*)sB2)[0 + half];
    const float4 b2q1 = ((const float4*)sB2)[2 + half];
    const float4 b2q2 = ((const float4*)sB2)[4 + half];
    const float4 b2q3 = ((const float4*)sB2)[6 + half];
    const float4 w3q0 = ((const float4*)sW3)[0 + half];
    const float4 w3q1 = ((const float4*)sW3)[2 + half];
    const float4 w3q2 = ((const float4*)sW3)[4 + half];
    const float4 w3q3 = ((const float4*)sW3)[6 + half];
    const float bias3 = b3[a];
    const f4pair w3p0 = __builtin_bit_cast(f4pair, w3q0);
    const f4pair w3p1 = __builtin_bit_cast(f4pair, w3q1);
    const f4pair w3p2 = __builtin_bit_cast(f4pair, w3q2);
    const f4pair w3p3 = __builtin_bit_cast(f4pair, w3q3);
    const f32x16 zacc = {0,0,0,0,0,0,0,0,0,0,0,0,0,0,0,0};
    // layer-2 bias accumulator: persistent, MFMA reads it non-destructively.
    const f32x16 b2acc = {b2q0.x, b2q0.y, b2q0.z, b2q0.w,
                          b2q1.x, b2q1.y, b2q1.z, b2q1.w,
                          b2q2.x, b2q2.y, b2q2.z, b2q2.w,
                          b2q3.x, b2q3.y, b2q3.z, b2q3.w};

    // g-frag build + L1 MFMAs (K slots: g0..g4, 1.0(bias), X, X; half-1
    // garbage words feed A's zeroed k=8..15 -> x*0 = 0, no masking).
    #define BUILD_L1(AX0, AX1, AX2, AX3, AX4) { \
        const unsigned gp01 = pack2(AX0, AX1); \
        const unsigned gp23 = pack2(AX2, AX3); \
        const unsigned gp45 = pack2(AX4, 1.0f); \
        auto gs01 = __builtin_amdgcn_permlane32_swap(gp01, gp01, false, false); \
        auto gs23 = __builtin_amdgcn_permlane32_swap(gp23, gp23, false, false); \
        auto gs45 = __builtin_amdgcn_permlane32_swap(gp45, gp45, false, false); \
        const uint4 bu0 = make_uint4(gp01,    gp23,    gp45,    0u); \
        const uint4 bu1 = make_uint4(gs01[1], gs23[1], gs45[1], 0u); \
        const short8 gb0 = __builtin_bit_cast(short8, bu0); \
        const short8 gb1 = __builtin_bit_cast(short8, bu1); \
        d0 = __builtin_amdgcn_mfma_f32_32x32x16_bf16(afl1, gb0, zacc, 0, 0, 0); \
        d1 = __builtin_amdgcn_mfma_f32_32x32x16_bf16(afl1, gb1, zacc, 0, 0, 0); }

    // prologue: g for it=0 (x*) and it=1 (y*); front-end of it=0.
    float x0g, x1g, x2g, x3g, x4g;
    float y0g, y1g, y2g, y3g, y4g;
    {
        const int s0 = sbase_blk + wid * 64 + lane;
        const float* gp = g + ((size_t)s0 * NA + a) * NI;
        x0g = gp[0]; x1g = gp[1]; x2g = gp[2]; x3g = gp[3]; x4g = gp[4];
        const int s1 = s0 + 256;                       // always < send for it=1
        const float* gq = g + ((size_t)s1 * NA + a) * NI;
        y0g = gq[0]; y1g = gq[1]; y2g = gq[2]; y3g = gq[3]; y4g = gq[4];
    }
    f32x16 d0, d1;
    BUILD_L1(x0g, x1g, x2g, x3g, x4g)

    #pragma unroll
    for (int it = 0; it < 4; ++it) {
        const int base = sbase_blk + it * 256 + wid * 64;
        const int s = base + lane;

        // ---- mid-layer: packed tanh + cvt_pk, permlane32_swap C->B ----
        // C row of reg r = (r&3) + 8*(r>>2) + 4*half. Packed word p[j] holds
        // rows {2j,2j+1} of this lane's row set. swap(a,b).x = {a_lo,b_lo},
        // .y = {a_hi,b_hi}: exactly B-frag words (k = half*8 + 2w, 2w+1).
        short8 bk0_0, bk1_0, bk0_1, bk1_1;
        #define TILE_CONV(DD, BK0, BK1) { \
            const unsigned p0 = tanh2_pack(DD[0],  DD[1]); \
            const unsigned p1 = tanh2_pack(DD[2],  DD[3]); \
            const unsigned p2 = tanh2_pack(DD[4],  DD[5]); \
            const unsigned p3 = tanh2_pack(DD[6],  DD[7]); \
            const unsigned p4 = tanh2_pack(DD[8],  DD[9]); \
            const unsigned p5 = tanh2_pack(DD[10], DD[11]); \
            const unsigned p6 = tanh2_pack(DD[12], DD[13]); \
            const unsigned p7 = tanh2_pack(DD[14], DD[15]); \
            auto s02 = __builtin_amdgcn_permlane32_swap(p0, p2, false, false); \
            auto s13 = __builtin_amdgcn_permlane32_swap(p1, p3, false, false); \
            auto s46 = __builtin_amdgcn_permlane32_swap(p4, p6, false, false); \
            auto s57 = __builtin_amdgcn_permlane32_swap(p5, p7, false, false); \
            const uint4 u0 = make_uint4(s02[0], s13[0], s02[1], s13[1]); \
            const uint4 u1 = make_uint4(s46[0], s57[0], s46[1], s57[1]); \
            BK0 = __builtin_bit_cast(short8, u0); \
            BK1 = __builtin_bit_cast(short8, u1); }
        TILE_CONV(d0, bk0_0, bk1_0)
        TILE_CONV(d1, bk0_1, bk1_1)
        #undef TILE_CONV
        // d0/d1 dead here; bk* live.

        // ---- PINNED next-iter front-end: fences stop the scheduler from
        // sinking these MFMAs to their use site (R14's silent failure). ----
        __builtin_amdgcn_sched_barrier(0);
        if (it < 3) {
            BUILD_L1(y0g, y1g, y2g, y3g, y4g)
        }
        __builtin_amdgcn_sched_barrier(0);

        // ---- layer 2 MFMA (bias via persistent b2acc) ----
        f32x16 acc0 = __builtin_amdgcn_mfma_f32_32x32x16_bf16(af0, bk0_0, b2acc, 0, 0, 0);
        acc0 = __builtin_amdgcn_mfma_f32_32x32x16_bf16(af1, bk1_0, acc0, 0, 0, 0);
        f32x16 acc1 = __builtin_amdgcn_mfma_f32_32x32x16_bf16(af0, bk0_1, b2acc, 0, 0, 0);
        acc1 = __builtin_amdgcn_mfma_f32_32x32x16_bf16(af1, bk1_1, acc1, 0, 0, 0);

        // refill y* for it+2 (full-iteration slack before consumption).
        if (it < 2) {
            const int sn = s + 512;
            const int sln = (sn < send) ? sn : (send - 1);
            const float* gq = g + ((size_t)sln * NA + a) * NI;
            y0g = gq[0]; y1g = gq[1]; y2g = gq[2]; y3g = gq[3]; y4g = gq[4];
        }

        // ---- epilogue: acc0 fully, then acc1 (early reg release); runs
        // concurrently with it+1's L1 MFMAs on the matrix pipe. ----
        const accpair ap0 = __builtin_bit_cast(accpair, acc0);
        f32x2 p0 = {0.f, 0.f};
        p0 += tanh_pk(ap0.p[0]) * w3p0.a;  p0 += tanh_pk(ap0.p[1]) * w3p0.b;
        p0 += tanh_pk(ap0.p[2]) * w3p1.a;  p0 += tanh_pk(ap0.p[3]) * w3p1.b;
        p0 += tanh_pk(ap0.p[4]) * w3p2.a;  p0 += tanh_pk(ap0.p[5]) * w3p2.b;
        p0 += tanh_pk(ap0.p[6]) * w3p3.a;  p0 += tanh_pk(ap0.p[7]) * w3p3.b;
        const float e0 = p0.x + p0.y;
        const accpair ap1 = __builtin_bit_cast(accpair, acc1);
        f32x2 p1 = {0.f, 0.f};
        p1 += tanh_pk(ap1.p[0]) * w3p0.a;  p1 += tanh_pk(ap1.p[1]) * w3p0.b;
        p1 += tanh_pk(ap1.p[2]) * w3p1.a;  p1 += tanh_pk(ap1.p[3]) * w3p1.b;
        p1 += tanh_pk(ap1.p[4]) * w3p2.a;  p1 += tanh_pk(ap1.p[5]) * w3p2.b;
        p1 += tanh_pk(ap1.p[6]) * w3p3.a;  p1 += tanh_pk(ap1.p[7]) * w3p3.b;
        const float e1 = p1.x + p1.y;
        // One swap fuses both cross-half reductions; every lane stores its
        // own struct: half0 lane l -> e0 sum (struct base+l), half1 -> e1.
        auto es = __builtin_amdgcn_permlane32_swap(__float_as_uint(e0),
                                                   __float_as_uint(e1),
                                                   false, false);
        const float etot = __uint_as_float(es[0]) + __uint_as_float(es[1]);
        if (s < send) out[(size_t)s * NA + a] = etot + bias3;
    }
    #undef BUILD_L1
}

extern "C" void kernel_launch(void* const* d_in, const int* in_sizes, int n_in,
                              void* d_out, int out_size, void* d_ws, size_t ws_size,
                              hipStream_t stream) {
    const float* g  = (const float*)d_in[0];
    const float* W1 = (const float*)d_in[1];
    const float* b1 = (const float*)d_in[2];
    const float* W2 = (const float*)d_in[3];
    const float* b2 = (const float*)d_in[4];
    const float* W3 = (const float*)d_in[5];
    const float* b3 = (const float*)d_in[6];
    float* out = (float*)d_out;
    mlp_mfma<<<dim3(NA * 2), dim3(256), 0, stream>>>(g, W1, b1, W2, b2, W3, b3, out);
}